// Round 1
// 629.634 us; speedup vs baseline: 1.0265x; 1.0265x over previous
//
#include <hip/hip_runtime.h>

// GATv2 x3 + MLP head on MI355X.
// R4: k_gat relayout 4 -> 8 channels/lane. One head (32ch) == one 4-lane quad
// for all layers, so the per-edge score reduce is 2 quad_perm DPP adds (VALU)
// instead of 3 chained ds_swizzles (LDS pipe). EPI doubles (2x edges in
// flight per wave), phases per node halve. 32-bit gather indices.

constexpr int N = 100000;
constexpr int E = 1600000;
constexpr int ET = N + E;   // edges + self loops
constexpr int S = 48;       // slots per node (cap; stores guarded)

// ---------------- graph build: one pass ----------------

__global__ __launch_bounds__(256) void k_build(const int* __restrict__ ei,
                                               int* __restrict__ deg,
                                               int* __restrict__ ebuf) {
  const int base = blockIdx.x * 1024 + threadIdx.x;
  int srcs[4], dsts[4];
  bool ok[4];
  #pragma unroll
  for (int j = 0; j < 4; ++j) {
    int e = base + j * 256;
    ok[j] = e < ET;
    int ec = ok[j] ? e : 0;
    if (ec < E) { srcs[j] = ei[ec]; dsts[j] = ei[E + ec]; }
    else        { srcs[j] = dsts[j] = ec - E; }
  }
  int pos[4];
  #pragma unroll
  for (int j = 0; j < 4; ++j) {  // 4 independent atomic chains in flight
    pos[j] = ok[j] ? atomicAdd(&deg[dsts[j]], 1) : S;
  }
  #pragma unroll
  for (int j = 0; j < 4; ++j) {
    if (pos[j] < S) ebuf[dsts[j] * S + pos[j]] = srcs[j];
  }
}

// ---------------- dense transform: y[n,M] = x[n,K] @ w[K,M] + b ----------------

template <int K, int M, int NB>
__global__ __launch_bounds__(256) void k_xform(const float* __restrict__ x,
                                               const float* __restrict__ w,
                                               const float* __restrict__ b,
                                               float* __restrict__ y) {
  constexpr int TPN = M / 4;       // channel threads per node group
  constexpr int NG = 256 / TPN;    // node groups per block
  constexpr int NPB = NG * NB;     // nodes per block (32)
  constexpr int KS = K + 1;        // padded row stride
  __shared__ float wl[K * M];
  __shared__ float xs[NPB * KS];
  const int tid = threadIdx.x;
  const float4* w4 = reinterpret_cast<const float4*>(w);
  float4* wl4 = reinterpret_cast<float4*>(wl);
  for (int i = tid; i < K * M / 4; i += 256) wl4[i] = w4[i];
  const int nbase = blockIdx.x * NPB;
  for (int i = tid; i < NPB * K; i += 256) {
    int ln = i / K, k = i & (K - 1);
    xs[ln * KS + k] = x[(size_t)(nbase + ln) * K + k];
  }
  __syncthreads();
  const int tn = tid % TPN;
  const int ng = tid / TPN;
  const float* xrow = xs + ng * NB * KS;
  float4 acc[NB];
  const float4 bv = *reinterpret_cast<const float4*>(b + tn * 4);
  #pragma unroll
  for (int j = 0; j < NB; ++j) acc[j] = bv;
  #pragma unroll 4
  for (int k = 0; k < K; ++k) {
    float4 wv = *reinterpret_cast<const float4*>(&wl[k * M + tn * 4]);
    #pragma unroll
    for (int j = 0; j < NB; ++j) {
      float xv = xrow[j * KS + k];
      acc[j].x += xv * wv.x; acc[j].y += xv * wv.y;
      acc[j].z += xv * wv.z; acc[j].w += xv * wv.w;
    }
  }
  #pragma unroll
  for (int j = 0; j < NB; ++j) {
    *reinterpret_cast<float4*>(y + (size_t)(nbase + ng * NB + j) * M + tn * 4) = acc[j];
  }
}

// ---------------- GATv2 aggregation: one wave per dst node ----------------
// Lane holds 8 features (2 x float4). One head (32 ch) == one 4-lane quad:
// score reduce = 2 quad_perm DPP adds, no LDS-pipe ops in the hot loop.
// EPI edges per phase (4/8/16); 2-stage decoupled pipeline as before.

template <int CTRL>
__device__ __forceinline__ float dpp_add(float x) {
  return x + __builtin_bit_cast(float,
      __builtin_amdgcn_update_dpp(0, __builtin_bit_cast(int, x),
                                  CTRL, 0xF, 0xF, true));
}

template <int H>
__global__ __launch_bounds__(256) void k_gat(const float* __restrict__ xl,
                                             const float* __restrict__ xr,
                                             const float* __restrict__ att,
                                             const float* __restrict__ bias,
                                             const int* __restrict__ deg,
                                             const int* __restrict__ ebuf,
                                             float* __restrict__ out) {
  constexpr int F = H * 32;
  constexpr int F4 = F / 4;        // float4 per row
  constexpr int LPE = F / 8;       // lanes per edge: 16 / 8 / 4
  constexpr int EPI = 64 / LPE;    // edges per iteration: 4 / 8 / 16
  constexpr float LOG2E = 1.44269504088896f;
  const int lane = threadIdx.x & 63;
  const int node = (blockIdx.x * blockDim.x + threadIdx.x) >> 6;
  if (node >= N) return;
  const int li = lane & (LPE - 1);
  const unsigned fidx = (unsigned)(li * 2);   // float4 index within row
  const int eg = lane / LPE;

  const float4* xl4 = reinterpret_cast<const float4*>(xl);
  const float4* xr4 = reinterpret_cast<const float4*>(xr);

  const unsigned nidx = (unsigned)node * (unsigned)F4 + fidx;
  const float4 xi0 = xr4[nidx];
  const float4 xi1 = xr4[nidx + 1];
  float4 at0 = reinterpret_cast<const float4*>(att)[fidx];
  float4 at1 = reinterpret_cast<const float4*>(att)[fidx + 1];
  at0.x *= LOG2E; at0.y *= LOG2E; at0.z *= LOG2E; at0.w *= LOG2E;
  at1.x *= LOG2E; at1.y *= LOG2E; at1.z *= LOG2E; at1.w *= LOG2E;

  float4 acc0 = make_float4(0.f, 0.f, 0.f, 0.f);
  float4 acc1 = make_float4(0.f, 0.f, 0.f, 0.f);
  float l = 0.f;

  const int* row = ebuf + node * S;
  const int dn = min(deg[node], S);   // deg >= 1 (self loop)
  const int last = dn - 1;
  const int iters = (dn + EPI - 1) / EPI;

  auto process = [&](const float4& j0, const float4& j1, bool valid) {
    float v0 = xi0.x + j0.x; v0 = fmaxf(v0, 0.2f * v0);
    float v1 = xi0.y + j0.y; v1 = fmaxf(v1, 0.2f * v1);
    float v2 = xi0.z + j0.z; v2 = fmaxf(v2, 0.2f * v2);
    float v3 = xi0.w + j0.w; v3 = fmaxf(v3, 0.2f * v3);
    float v4 = xi1.x + j1.x; v4 = fmaxf(v4, 0.2f * v4);
    float v5 = xi1.y + j1.y; v5 = fmaxf(v5, 0.2f * v5);
    float v6 = xi1.z + j1.z; v6 = fmaxf(v6, 0.2f * v6);
    float v7 = xi1.w + j1.w; v7 = fmaxf(v7, 0.2f * v7);
    float t = at0.x * v0;
    t = fmaf(at0.y, v1, t);
    t = fmaf(at0.z, v2, t);
    t = fmaf(at0.w, v3, t);
    t = fmaf(at1.x, v4, t);
    t = fmaf(at1.y, v5, t);
    t = fmaf(at1.z, v6, t);
    t = fmaf(at1.w, v7, t);
    // head = one 4-lane quad: butterfly via quad_perm DPP (VALU, no LDS pipe)
    t = dpp_add<0xB1>(t);   // xor 1: [1,0,3,2]
    t = dpp_add<0x4E>(t);   // xor 2: [2,3,0,1]
    float pm = valid ? exp2f(t) : 0.f;
    l += pm;
    acc0.x = fmaf(pm, j0.x, acc0.x); acc0.y = fmaf(pm, j0.y, acc0.y);
    acc0.z = fmaf(pm, j0.z, acc0.z); acc0.w = fmaf(pm, j0.w, acc0.w);
    acc1.x = fmaf(pm, j1.x, acc1.x); acc1.y = fmaf(pm, j1.y, acc1.y);
    acc1.z = fmaf(pm, j1.z, acc1.z); acc1.w = fmaf(pm, j1.w, acc1.w);
  };

  // pipeline warm-up
  int i = eg;
  bool vA = i < dn;
  {
    int s = row[min(i, last)];
    unsigned r = (unsigned)s * (unsigned)F4 + fidx;
    // gather it0 happens below via xjA
    i += EPI;
    bool vB0 = i < dn;
    (void)vB0;
    // load it0
    float4 a0 = xl4[r], a1 = xl4[r + 1];
    // fallthrough into named regs
    // (written this way to keep the 2-stage structure below)
    // store into pipeline regs:
    // xjA = it0
    // sN  = src of it1
    // continue below
    // --- actual pipeline state ---
    float4 xjA0 = a0, xjA1 = a1;
    bool vBv = i < dn;
    int sN = row[min(i, last)];
    i += EPI;
    float4 xjB0, xjB1;
    bool vB = vBv;

    for (int it = 0; it < iters; it += 2) {
      // ---- phase A: consume (xjA, vA) = iteration it ----
      {
        unsigned rn = (unsigned)sN * (unsigned)F4 + fidx;
        xjB0 = xl4[rn]; xjB1 = xl4[rn + 1];          // gather it+1
      }
      bool vn = i < dn;
      sN = row[min(i, last)];                        // src it+2
      i += EPI;
      process(xjA0, xjA1, vA);
      vA = vn;
      // ---- phase B: consume (xjB, vB) = iteration it+1 ----
      {
        unsigned rn = (unsigned)sN * (unsigned)F4 + fidx;
        xjA0 = xl4[rn]; xjA1 = xl4[rn + 1];          // gather it+2
      }
      vn = i < dn;
      sN = row[min(i, last)];                        // src it+3
      i += EPI;
      process(xjB0, xjB1, vB);
      vB = vn;
    }
  }

  // combine the EPI edge slots (once per node)
  #pragma unroll
  for (int ofs = LPE; ofs < 64; ofs <<= 1) {
    acc0.x += __shfl_xor(acc0.x, ofs);
    acc0.y += __shfl_xor(acc0.y, ofs);
    acc0.z += __shfl_xor(acc0.z, ofs);
    acc0.w += __shfl_xor(acc0.w, ofs);
    acc1.x += __shfl_xor(acc1.x, ofs);
    acc1.y += __shfl_xor(acc1.y, ofs);
    acc1.z += __shfl_xor(acc1.z, ofs);
    acc1.w += __shfl_xor(acc1.w, ofs);
    l      += __shfl_xor(l, ofs);
  }

  if (lane < LPE) {
    const float inv = 1.f / (l + 1e-16f);
    const float4 bv0 = reinterpret_cast<const float4*>(bias)[fidx];
    const float4 bv1 = reinterpret_cast<const float4*>(bias)[fidx + 1];
    float4 r0, r1;
    r0.x = fmaxf(acc0.x * inv + bv0.x, 0.f);
    r0.y = fmaxf(acc0.y * inv + bv0.y, 0.f);
    r0.z = fmaxf(acc0.z * inv + bv0.z, 0.f);
    r0.w = fmaxf(acc0.w * inv + bv0.w, 0.f);
    r1.x = fmaxf(acc1.x * inv + bv1.x, 0.f);
    r1.y = fmaxf(acc1.y * inv + bv1.y, 0.f);
    r1.z = fmaxf(acc1.z * inv + bv1.z, 0.f);
    r1.w = fmaxf(acc1.w * inv + bv1.w, 0.f);
    float4* op = reinterpret_cast<float4*>(out) + nidx;
    op[0] = r0;
    op[1] = r1;
  }
}

// ---------------- MLP head + output transforms ----------------

__global__ __launch_bounds__(256) void k_mlp(const float* __restrict__ h,
                                             const float* __restrict__ wm1,
                                             const float* __restrict__ bm1,
                                             const float* __restrict__ wm2,
                                             const float* __restrict__ bm2,
                                             float* __restrict__ out) {
  __shared__ float w1[512], b1[16], w2[32], b2[2];
  const int tid = threadIdx.x;
  for (int i = tid; i < 512; i += 256) w1[i] = wm1[i];
  if (tid < 16) b1[tid] = bm1[tid];
  if (tid < 32) w2[tid] = wm2[tid];
  if (tid < 2)  b2[tid] = bm2[tid];
  __syncthreads();
  const int node = blockIdx.x * blockDim.x + tid;
  if (node >= N) return;
  float hv[32];
  const float* hp = h + (size_t)node * 32;
  #pragma unroll
  for (int k = 0; k < 8; ++k) {
    float4 v = reinterpret_cast<const float4*>(hp)[k];
    hv[4 * k] = v.x; hv[4 * k + 1] = v.y; hv[4 * k + 2] = v.z; hv[4 * k + 3] = v.w;
  }
  float r0 = b2[0], r1 = b2[1];
  #pragma unroll
  for (int j = 0; j < 16; ++j) {
    float a = b1[j];
    #pragma unroll
    for (int k = 0; k < 32; ++k) a += hv[k] * w1[k * 16 + j];
    a = fmaxf(a, 0.f);
    r0 += a * w2[j * 2];
    r1 += a * w2[j * 2 + 1];
  }
  float vm = 1.f / (1.f + __expf(-r0)) + 0.5f;
  float va = tanhf(r1) * 180.f;
  out[(size_t)node * 2]     = vm;
  out[(size_t)node * 2 + 1] = va;
}

// ---------------- launch ----------------

extern "C" void kernel_launch(void* const* d_in, const int* in_sizes, int n_in,
                              void* d_out, int out_size, void* d_ws, size_t ws_size,
                              hipStream_t stream) {
  const float* x   = (const float*)d_in[0];
  const int*   ei  = (const int*)d_in[1];
  const float* w1l = (const float*)d_in[2];
  const float* b1l = (const float*)d_in[3];
  const float* w1r = (const float*)d_in[4];
  const float* b1r = (const float*)d_in[5];
  const float* a1  = (const float*)d_in[6];
  const float* c1  = (const float*)d_in[7];
  const float* w2l = (const float*)d_in[8];
  const float* b2l = (const float*)d_in[9];
  const float* w2r = (const float*)d_in[10];
  const float* b2r = (const float*)d_in[11];
  const float* a2  = (const float*)d_in[12];
  const float* c2  = (const float*)d_in[13];
  const float* w3l = (const float*)d_in[14];
  const float* b3l = (const float*)d_in[15];
  const float* w3r = (const float*)d_in[16];
  const float* b3r = (const float*)d_in[17];
  const float* a3  = (const float*)d_in[18];
  const float* c3  = (const float*)d_in[19];
  const float* wm1 = (const float*)d_in[20];
  const float* bm1 = (const float*)d_in[21];
  const float* wm2 = (const float*)d_in[22];
  const float* bm2 = (const float*)d_in[23];
  float* outp = (float*)d_out;
  (void)in_sizes; (void)n_in; (void)out_size; (void)ws_size;

  char* ws = (char*)d_ws;
  size_t o = 0;
  auto take = [&](size_t bytes) {
    char* p = ws + o;
    o = (o + bytes + 255) & ~(size_t)255;
    return p;
  };
  int* deg    = (int*)take((size_t)N * sizeof(int));
  int* ebuf   = (int*)take((size_t)N * S * sizeof(int));
  float* A    = (float*)take((size_t)N * 128 * sizeof(float));  // xl
  float* B    = (float*)take((size_t)N * 128 * sizeof(float));  // xr
  float* Cb   = (float*)take((size_t)N * 128 * sizeof(float));  // h (layer out)

  // --- graph build (one atomic pass, shared across all 3 layers) ---
  hipMemsetAsync(deg, 0, (size_t)N * sizeof(int), stream);
  k_build<<<(ET + 1023) / 1024, 256, 0, stream>>>(ei, deg, ebuf);

  // --- layer 1: 64 -> (4 heads x 32), concat ---
  k_xform<64, 128, 4><<<N / 32, 256, 0, stream>>>(x, w1l, b1l, A);
  k_xform<64, 128, 4><<<N / 32, 256, 0, stream>>>(x, w1r, b1r, B);
  k_gat<4><<<N / 4, 256, 0, stream>>>(A, B, a1, c1, deg, ebuf, Cb);

  // --- layer 2: 128 -> (2 heads x 32), concat ---
  k_xform<128, 64, 2><<<N / 32, 256, 0, stream>>>(Cb, w2l, b2l, A);
  k_xform<128, 64, 2><<<N / 32, 256, 0, stream>>>(Cb, w2r, b2r, B);
  k_gat<2><<<N / 4, 256, 0, stream>>>(A, B, a2, c2, deg, ebuf, Cb);

  // --- layer 3: 64 -> (1 head x 32), mean over 1 head == identity ---
  k_xform<64, 32, 1><<<N / 32, 256, 0, stream>>>(Cb, w3l, b3l, A);
  k_xform<64, 32, 1><<<N / 32, 256, 0, stream>>>(Cb, w3r, b3r, B);
  k_gat<1><<<N / 4, 256, 0, stream>>>(A, B, a3, c3, deg, ebuf, Cb);

  // --- MLP head + sigmoid/tanh ---
  k_mlp<<<(N + 255) / 256, 256, 0, stream>>>(Cb, wm1, bm1, wm2, bm2, outp);
}

// Round 2
// 571.459 us; speedup vs baseline: 1.1310x; 1.1018x over previous
//
#include <hip/hip_runtime.h>
#include <hip/hip_fp16.h>

// GATv2 x3 + MLP head on MI355X.
// R5: xl/xr (the gathered feature tables) stored in fp16. k_gat is gather-
// traffic bound (FETCH 430MB = 3.5x compulsory, 3.86 TB/s random-access
// plateau); halving the row size halves both bytes and requests. All math
// and the layer outputs (Cb) remain fp32 - quantization is once per layer.

constexpr int N = 100000;
constexpr int E = 1600000;
constexpr int ET = N + E;   // edges + self loops
constexpr int S = 48;       // slots per node (cap; stores guarded)

// ---------------- graph build: one pass ----------------

__global__ __launch_bounds__(256) void k_build(const int* __restrict__ ei,
                                               int* __restrict__ deg,
                                               int* __restrict__ ebuf) {
  const int base = blockIdx.x * 1024 + threadIdx.x;
  int srcs[4], dsts[4];
  bool ok[4];
  #pragma unroll
  for (int j = 0; j < 4; ++j) {
    int e = base + j * 256;
    ok[j] = e < ET;
    int ec = ok[j] ? e : 0;
    if (ec < E) { srcs[j] = ei[ec]; dsts[j] = ei[E + ec]; }
    else        { srcs[j] = dsts[j] = ec - E; }
  }
  int pos[4];
  #pragma unroll
  for (int j = 0; j < 4; ++j) {  // 4 independent atomic chains in flight
    pos[j] = ok[j] ? atomicAdd(&deg[dsts[j]], 1) : S;
  }
  #pragma unroll
  for (int j = 0; j < 4; ++j) {
    if (pos[j] < S) ebuf[dsts[j] * S + pos[j]] = srcs[j];
  }
}

// ---------------- dense transform: y[n,M] = x[n,K] @ w[K,M] + b (half out) ----

template <int K, int M, int NB>
__global__ __launch_bounds__(256) void k_xform(const float* __restrict__ x,
                                               const float* __restrict__ w,
                                               const float* __restrict__ b,
                                               __half* __restrict__ y) {
  constexpr int TPN = M / 4;       // channel threads per node group
  constexpr int NG = 256 / TPN;    // node groups per block
  constexpr int NPB = NG * NB;     // nodes per block (32)
  constexpr int KS = K + 1;        // padded row stride
  __shared__ float wl[K * M];
  __shared__ float xs[NPB * KS];
  const int tid = threadIdx.x;
  const float4* w4 = reinterpret_cast<const float4*>(w);
  float4* wl4 = reinterpret_cast<float4*>(wl);
  for (int i = tid; i < K * M / 4; i += 256) wl4[i] = w4[i];
  const int nbase = blockIdx.x * NPB;
  for (int i = tid; i < NPB * K; i += 256) {
    int ln = i / K, k = i & (K - 1);
    xs[ln * KS + k] = x[(size_t)(nbase + ln) * K + k];
  }
  __syncthreads();
  const int tn = tid % TPN;
  const int ng = tid / TPN;
  const float* xrow = xs + ng * NB * KS;
  float4 acc[NB];
  const float4 bv = *reinterpret_cast<const float4*>(b + tn * 4);
  #pragma unroll
  for (int j = 0; j < NB; ++j) acc[j] = bv;
  #pragma unroll 4
  for (int k = 0; k < K; ++k) {
    float4 wv = *reinterpret_cast<const float4*>(&wl[k * M + tn * 4]);
    #pragma unroll
    for (int j = 0; j < NB; ++j) {
      float xv = xrow[j * KS + k];
      acc[j].x += xv * wv.x; acc[j].y += xv * wv.y;
      acc[j].z += xv * wv.z; acc[j].w += xv * wv.w;
    }
  }
  #pragma unroll
  for (int j = 0; j < NB; ++j) {
    __half2 p0 = __float22half2_rn(make_float2(acc[j].x, acc[j].y));
    __half2 p1 = __float22half2_rn(make_float2(acc[j].z, acc[j].w));
    uint2 pk = make_uint2(__builtin_bit_cast(unsigned, p0),
                          __builtin_bit_cast(unsigned, p1));
    *reinterpret_cast<uint2*>(y + (size_t)(nbase + ng * NB + j) * M + tn * 4) = pk;
  }
}

// ---------------- GATv2 aggregation: one wave per dst node ----------------
// Lane holds 8 fp16 features = one 16B gather per edge (was 32B fp32).
// One head (32 ch) == one 4-lane quad: score reduce = 2 quad_perm DPP adds.
// EPI edges per phase (4/8/16); 2-stage decoupled pipeline.

template <int CTRL>
__device__ __forceinline__ float dpp_add(float x) {
  return x + __builtin_bit_cast(float,
      __builtin_amdgcn_update_dpp(0, __builtin_bit_cast(int, x),
                                  CTRL, 0xF, 0xF, true));
}

__device__ __forceinline__ void cvt8(const uint4 r, float4& a, float4& b) {
  float2 f;
  f = __half22float2(__builtin_bit_cast(__half2, r.x)); a.x = f.x; a.y = f.y;
  f = __half22float2(__builtin_bit_cast(__half2, r.y)); a.z = f.x; a.w = f.y;
  f = __half22float2(__builtin_bit_cast(__half2, r.z)); b.x = f.x; b.y = f.y;
  f = __half22float2(__builtin_bit_cast(__half2, r.w)); b.z = f.x; b.w = f.y;
}

template <int H>
__global__ __launch_bounds__(256) void k_gat(const __half* __restrict__ xl,
                                             const __half* __restrict__ xr,
                                             const float* __restrict__ att,
                                             const float* __restrict__ bias,
                                             const int* __restrict__ deg,
                                             const int* __restrict__ ebuf,
                                             float* __restrict__ out) {
  constexpr int F = H * 32;
  constexpr int F8 = F / 8;        // 16B chunks (8 halfs) per row
  constexpr int F4 = F / 4;        // float4 per fp32 out row
  constexpr int LPE = F8;          // lanes per edge: 16 / 8 / 4
  constexpr int EPI = 64 / LPE;    // edges per iteration: 4 / 8 / 16
  constexpr float LOG2E = 1.44269504088896f;
  const int lane = threadIdx.x & 63;
  const int node = (blockIdx.x * blockDim.x + threadIdx.x) >> 6;
  if (node >= N) return;
  const int li = lane & (LPE - 1);  // 16B chunk index within row
  const int eg = lane / LPE;

  const uint4* xl4 = reinterpret_cast<const uint4*>(xl);
  const uint4* xr4 = reinterpret_cast<const uint4*>(xr);

  float4 xi0, xi1;
  cvt8(xr4[(unsigned)node * F8 + li], xi0, xi1);
  float4 at0 = reinterpret_cast<const float4*>(att)[li * 2];
  float4 at1 = reinterpret_cast<const float4*>(att)[li * 2 + 1];
  at0.x *= LOG2E; at0.y *= LOG2E; at0.z *= LOG2E; at0.w *= LOG2E;
  at1.x *= LOG2E; at1.y *= LOG2E; at1.z *= LOG2E; at1.w *= LOG2E;

  float4 acc0 = make_float4(0.f, 0.f, 0.f, 0.f);
  float4 acc1 = make_float4(0.f, 0.f, 0.f, 0.f);
  float l = 0.f;

  const int* row = ebuf + node * S;
  const int dn = min(deg[node], S);   // deg >= 1 (self loop)
  const int last = dn - 1;
  const int iters = (dn + EPI - 1) / EPI;

  auto process = [&](const uint4& raw, bool valid) {
    float4 j0, j1;
    cvt8(raw, j0, j1);
    float v0 = xi0.x + j0.x; v0 = fmaxf(v0, 0.2f * v0);
    float v1 = xi0.y + j0.y; v1 = fmaxf(v1, 0.2f * v1);
    float v2 = xi0.z + j0.z; v2 = fmaxf(v2, 0.2f * v2);
    float v3 = xi0.w + j0.w; v3 = fmaxf(v3, 0.2f * v3);
    float v4 = xi1.x + j1.x; v4 = fmaxf(v4, 0.2f * v4);
    float v5 = xi1.y + j1.y; v5 = fmaxf(v5, 0.2f * v5);
    float v6 = xi1.z + j1.z; v6 = fmaxf(v6, 0.2f * v6);
    float v7 = xi1.w + j1.w; v7 = fmaxf(v7, 0.2f * v7);
    float t = at0.x * v0;
    t = fmaf(at0.y, v1, t);
    t = fmaf(at0.z, v2, t);
    t = fmaf(at0.w, v3, t);
    t = fmaf(at1.x, v4, t);
    t = fmaf(at1.y, v5, t);
    t = fmaf(at1.z, v6, t);
    t = fmaf(at1.w, v7, t);
    // head = one 4-lane quad: butterfly via quad_perm DPP (VALU, no LDS pipe)
    t = dpp_add<0xB1>(t);   // xor 1: [1,0,3,2]
    t = dpp_add<0x4E>(t);   // xor 2: [2,3,0,1]
    float pm = valid ? exp2f(t) : 0.f;
    l += pm;
    acc0.x = fmaf(pm, j0.x, acc0.x); acc0.y = fmaf(pm, j0.y, acc0.y);
    acc0.z = fmaf(pm, j0.z, acc0.z); acc0.w = fmaf(pm, j0.w, acc0.w);
    acc1.x = fmaf(pm, j1.x, acc1.x); acc1.y = fmaf(pm, j1.y, acc1.y);
    acc1.z = fmaf(pm, j1.z, acc1.z); acc1.w = fmaf(pm, j1.w, acc1.w);
  };

  // pipeline warm-up: src prefetched 2 iterations ahead, gather 1 ahead
  int i = eg;
  bool vA = i < dn;
  int s0 = row[min(i, last)];
  i += EPI;
  uint4 xjA = xl4[(unsigned)s0 * F8 + li];
  bool vB = i < dn;
  int sN = row[min(i, last)];
  i += EPI;
  uint4 xjB;

  for (int it = 0; it < iters; it += 2) {
    // ---- phase A: consume (xjA, vA) = iteration it ----
    xjB = xl4[(unsigned)sN * F8 + li];             // gather it+1
    bool vn = i < dn;
    sN = row[min(i, last)];                        // src it+2
    i += EPI;
    process(xjA, vA);
    vA = vn;
    // ---- phase B: consume (xjB, vB) = iteration it+1 ----
    xjA = xl4[(unsigned)sN * F8 + li];             // gather it+2
    vn = i < dn;
    sN = row[min(i, last)];                        // src it+3
    i += EPI;
    process(xjB, vB);
    vB = vn;
  }

  // combine the EPI edge slots (once per node)
  #pragma unroll
  for (int ofs = LPE; ofs < 64; ofs <<= 1) {
    acc0.x += __shfl_xor(acc0.x, ofs);
    acc0.y += __shfl_xor(acc0.y, ofs);
    acc0.z += __shfl_xor(acc0.z, ofs);
    acc0.w += __shfl_xor(acc0.w, ofs);
    acc1.x += __shfl_xor(acc1.x, ofs);
    acc1.y += __shfl_xor(acc1.y, ofs);
    acc1.z += __shfl_xor(acc1.z, ofs);
    acc1.w += __shfl_xor(acc1.w, ofs);
    l      += __shfl_xor(l, ofs);
  }

  if (lane < LPE) {
    const float inv = 1.f / (l + 1e-16f);
    const float4 bv0 = reinterpret_cast<const float4*>(bias)[li * 2];
    const float4 bv1 = reinterpret_cast<const float4*>(bias)[li * 2 + 1];
    float4 r0, r1;
    r0.x = fmaxf(acc0.x * inv + bv0.x, 0.f);
    r0.y = fmaxf(acc0.y * inv + bv0.y, 0.f);
    r0.z = fmaxf(acc0.z * inv + bv0.z, 0.f);
    r0.w = fmaxf(acc0.w * inv + bv0.w, 0.f);
    r1.x = fmaxf(acc1.x * inv + bv1.x, 0.f);
    r1.y = fmaxf(acc1.y * inv + bv1.y, 0.f);
    r1.z = fmaxf(acc1.z * inv + bv1.z, 0.f);
    r1.w = fmaxf(acc1.w * inv + bv1.w, 0.f);
    float4* op = reinterpret_cast<float4*>(out) + (unsigned)node * F4 + li * 2;
    op[0] = r0;
    op[1] = r1;
  }
}

// ---------------- MLP head + output transforms ----------------

__global__ __launch_bounds__(256) void k_mlp(const float* __restrict__ h,
                                             const float* __restrict__ wm1,
                                             const float* __restrict__ bm1,
                                             const float* __restrict__ wm2,
                                             const float* __restrict__ bm2,
                                             float* __restrict__ out) {
  __shared__ float w1[512], b1[16], w2[32], b2[2];
  const int tid = threadIdx.x;
  for (int i = tid; i < 512; i += 256) w1[i] = wm1[i];
  if (tid < 16) b1[tid] = bm1[tid];
  if (tid < 32) w2[tid] = wm2[tid];
  if (tid < 2)  b2[tid] = bm2[tid];
  __syncthreads();
  const int node = blockIdx.x * blockDim.x + tid;
  if (node >= N) return;
  float hv[32];
  const float* hp = h + (size_t)node * 32;
  #pragma unroll
  for (int k = 0; k < 8; ++k) {
    float4 v = reinterpret_cast<const float4*>(hp)[k];
    hv[4 * k] = v.x; hv[4 * k + 1] = v.y; hv[4 * k + 2] = v.z; hv[4 * k + 3] = v.w;
  }
  float r0 = b2[0], r1 = b2[1];
  #pragma unroll
  for (int j = 0; j < 16; ++j) {
    float a = b1[j];
    #pragma unroll
    for (int k = 0; k < 32; ++k) a += hv[k] * w1[k * 16 + j];
    a = fmaxf(a, 0.f);
    r0 += a * w2[j * 2];
    r1 += a * w2[j * 2 + 1];
  }
  float vm = 1.f / (1.f + __expf(-r0)) + 0.5f;
  float va = tanhf(r1) * 180.f;
  out[(size_t)node * 2]     = vm;
  out[(size_t)node * 2 + 1] = va;
}

// ---------------- launch ----------------

extern "C" void kernel_launch(void* const* d_in, const int* in_sizes, int n_in,
                              void* d_out, int out_size, void* d_ws, size_t ws_size,
                              hipStream_t stream) {
  const float* x   = (const float*)d_in[0];
  const int*   ei  = (const int*)d_in[1];
  const float* w1l = (const float*)d_in[2];
  const float* b1l = (const float*)d_in[3];
  const float* w1r = (const float*)d_in[4];
  const float* b1r = (const float*)d_in[5];
  const float* a1  = (const float*)d_in[6];
  const float* c1  = (const float*)d_in[7];
  const float* w2l = (const float*)d_in[8];
  const float* b2l = (const float*)d_in[9];
  const float* w2r = (const float*)d_in[10];
  const float* b2r = (const float*)d_in[11];
  const float* a2  = (const float*)d_in[12];
  const float* c2  = (const float*)d_in[13];
  const float* w3l = (const float*)d_in[14];
  const float* b3l = (const float*)d_in[15];
  const float* w3r = (const float*)d_in[16];
  const float* b3r = (const float*)d_in[17];
  const float* a3  = (const float*)d_in[18];
  const float* c3  = (const float*)d_in[19];
  const float* wm1 = (const float*)d_in[20];
  const float* bm1 = (const float*)d_in[21];
  const float* wm2 = (const float*)d_in[22];
  const float* bm2 = (const float*)d_in[23];
  float* outp = (float*)d_out;
  (void)in_sizes; (void)n_in; (void)out_size; (void)ws_size;

  char* ws = (char*)d_ws;
  size_t o = 0;
  auto take = [&](size_t bytes) {
    char* p = ws + o;
    o = (o + bytes + 255) & ~(size_t)255;
    return p;
  };
  int* deg    = (int*)take((size_t)N * sizeof(int));
  int* ebuf   = (int*)take((size_t)N * S * sizeof(int));
  __half* A   = (__half*)take((size_t)N * 128 * sizeof(__half));  // xl (fp16)
  __half* B   = (__half*)take((size_t)N * 128 * sizeof(__half));  // xr (fp16)
  float* Cb   = (float*)take((size_t)N * 128 * sizeof(float));    // h (layer out)

  // --- graph build (one atomic pass, shared across all 3 layers) ---
  hipMemsetAsync(deg, 0, (size_t)N * sizeof(int), stream);
  k_build<<<(ET + 1023) / 1024, 256, 0, stream>>>(ei, deg, ebuf);

  // --- layer 1: 64 -> (4 heads x 32), concat ---
  k_xform<64, 128, 4><<<N / 32, 256, 0, stream>>>(x, w1l, b1l, A);
  k_xform<64, 128, 4><<<N / 32, 256, 0, stream>>>(x, w1r, b1r, B);
  k_gat<4><<<N / 4, 256, 0, stream>>>(A, B, a1, c1, deg, ebuf, Cb);

  // --- layer 2: 128 -> (2 heads x 32), concat ---
  k_xform<128, 64, 2><<<N / 32, 256, 0, stream>>>(Cb, w2l, b2l, A);
  k_xform<128, 64, 2><<<N / 32, 256, 0, stream>>>(Cb, w2r, b2r, B);
  k_gat<2><<<N / 4, 256, 0, stream>>>(A, B, a2, c2, deg, ebuf, Cb);

  // --- layer 3: 64 -> (1 head x 32), mean over 1 head == identity ---
  k_xform<64, 32, 1><<<N / 32, 256, 0, stream>>>(Cb, w3l, b3l, A);
  k_xform<64, 32, 1><<<N / 32, 256, 0, stream>>>(Cb, w3r, b3r, B);
  k_gat<1><<<N / 4, 256, 0, stream>>>(A, B, a3, c3, deg, ebuf, Cb);

  // --- MLP head + sigmoid/tanh ---
  k_mlp<<<(N + 255) / 256, 256, 0, stream>>>(Cb, wm1, bm1, wm2, bm2, outp);
}

// Round 3
// 546.710 us; speedup vs baseline: 1.1822x; 1.0453x over previous
//
#include <hip/hip_runtime.h>
#include <hip/hip_fp16.h>

// GATv2 x3 + MLP head on MI355X.
// R6: k_build (105us, atomic-latency-bound, CUs idle) fused with the layer-1
// L/R transforms as a heterogeneous grid: build blocks first, xform blocks
// fill idle slots. k_xform drops the xs LDS staging (direct L1-broadcast x
// reads) so LDS=32KB -> 5 blocks/CU, preserving build concurrency in the
// fused kernel. L+R transform pairs fused to one launch per layer.

constexpr int N = 100000;
constexpr int E = 1600000;
constexpr int ET = N + E;   // edges + self loops
constexpr int S = 48;       // slots per node (cap; stores guarded)

constexpr int BUILD_B = (ET + 1023) / 1024;  // build blocks (1024 edges each)
constexpr int XF_B = N / 32;                  // xform blocks (32 nodes each)

// ---------------- graph build body: one atomic pass ----------------

__device__ __forceinline__ void build_body(const int* __restrict__ ei,
                                           int* __restrict__ deg,
                                           int* __restrict__ ebuf,
                                           int blk) {
  const int base = blk * 1024 + threadIdx.x;
  int srcs[4], dsts[4];
  bool ok[4];
  #pragma unroll
  for (int j = 0; j < 4; ++j) {
    int e = base + j * 256;
    ok[j] = e < ET;
    int ec = ok[j] ? e : 0;
    if (ec < E) { srcs[j] = ei[ec]; dsts[j] = ei[E + ec]; }
    else        { srcs[j] = dsts[j] = ec - E; }
  }
  int pos[4];
  #pragma unroll
  for (int j = 0; j < 4; ++j) {  // 4 independent atomic chains in flight
    pos[j] = ok[j] ? atomicAdd(&deg[dsts[j]], 1) : S;
  }
  #pragma unroll
  for (int j = 0; j < 4; ++j) {
    if (pos[j] < S) ebuf[dsts[j] * S + pos[j]] = srcs[j];
  }
}

// ---------------- dense transform body: y[n,M] = x[n,K] @ w[K,M] + b ---------
// No x staging: x reads are uniform within a node-group (L1 broadcast).
// LDS = weights only (32KB for layers 1/2) -> 5 blocks/CU.

template <int K, int M, int NB>
__device__ __forceinline__ void xform_body(const float* __restrict__ x,
                                           const float* __restrict__ w,
                                           const float* __restrict__ b,
                                           __half* __restrict__ y, int blk) {
  constexpr int TPN = M / 4;       // channel threads per node group
  constexpr int NG = 256 / TPN;    // node groups per block
  constexpr int NPB = NG * NB;     // nodes per block (32)
  __shared__ float wl[K * M];
  const int tid = threadIdx.x;
  const float4* w4 = reinterpret_cast<const float4*>(w);
  float4* wl4 = reinterpret_cast<float4*>(wl);
  for (int i = tid; i < K * M / 4; i += 256) wl4[i] = w4[i];
  __syncthreads();
  const int nbase = blk * NPB;
  const int tn = tid % TPN;
  const int ng = tid / TPN;
  const float* xrow = x + (size_t)(nbase + ng * NB) * K;
  float4 acc[NB];
  const float4 bv = *reinterpret_cast<const float4*>(b + tn * 4);
  #pragma unroll
  for (int j = 0; j < NB; ++j) acc[j] = bv;
  #pragma unroll 4
  for (int k = 0; k < K; ++k) {
    float4 wv = *reinterpret_cast<const float4*>(&wl[k * M + tn * 4]);
    #pragma unroll
    for (int j = 0; j < NB; ++j) {
      float xv = xrow[j * K + k];
      acc[j].x += xv * wv.x; acc[j].y += xv * wv.y;
      acc[j].z += xv * wv.z; acc[j].w += xv * wv.w;
    }
  }
  #pragma unroll
  for (int j = 0; j < NB; ++j) {
    __half2 p0 = __float22half2_rn(make_float2(acc[j].x, acc[j].y));
    __half2 p1 = __float22half2_rn(make_float2(acc[j].z, acc[j].w));
    uint2 pk = make_uint2(__builtin_bit_cast(unsigned, p0),
                          __builtin_bit_cast(unsigned, p1));
    *reinterpret_cast<uint2*>(y + (size_t)(nbase + ng * NB + j) * M + tn * 4) = pk;
  }
}

// ---------------- fused layer-1: build + xform L + xform R ----------------

__global__ __launch_bounds__(256) void k_l1(const float* __restrict__ x,
                                            const float* __restrict__ wlp,
                                            const float* __restrict__ blp,
                                            const float* __restrict__ wrp,
                                            const float* __restrict__ brp,
                                            __half* __restrict__ A,
                                            __half* __restrict__ B,
                                            const int* __restrict__ ei,
                                            int* __restrict__ deg,
                                            int* __restrict__ ebuf) {
  int blk = blockIdx.x;
  if (blk < BUILD_B) { build_body(ei, deg, ebuf, blk); return; }
  blk -= BUILD_B;
  const bool right = blk >= XF_B;
  const int xblk = right ? blk - XF_B : blk;
  xform_body<64, 128, 4>(x, right ? wrp : wlp, right ? brp : blp,
                         right ? B : A, xblk);
}

// ---------------- fused L+R transform (layers 2 and 3) ----------------

template <int K, int M, int NB>
__global__ __launch_bounds__(256) void k_xform2(const float* __restrict__ x,
                                                const float* __restrict__ wlp,
                                                const float* __restrict__ blp,
                                                const float* __restrict__ wrp,
                                                const float* __restrict__ brp,
                                                __half* __restrict__ A,
                                                __half* __restrict__ B) {
  int blk = blockIdx.x;
  const bool right = blk >= XF_B;
  const int xblk = right ? blk - XF_B : blk;
  xform_body<K, M, NB>(x, right ? wrp : wlp, right ? brp : blp,
                       right ? B : A, xblk);
}

// ---------------- GATv2 aggregation: one wave per dst node ----------------
// Lane holds 8 fp16 features = one 16B gather per edge.
// One head (32 ch) == one 4-lane quad: score reduce = 2 quad_perm DPP adds.
// EPI edges per phase (4/8/16); 2-stage decoupled pipeline.

template <int CTRL>
__device__ __forceinline__ float dpp_add(float x) {
  return x + __builtin_bit_cast(float,
      __builtin_amdgcn_update_dpp(0, __builtin_bit_cast(int, x),
                                  CTRL, 0xF, 0xF, true));
}

__device__ __forceinline__ void cvt8(const uint4 r, float4& a, float4& b) {
  float2 f;
  f = __half22float2(__builtin_bit_cast(__half2, r.x)); a.x = f.x; a.y = f.y;
  f = __half22float2(__builtin_bit_cast(__half2, r.y)); a.z = f.x; a.w = f.y;
  f = __half22float2(__builtin_bit_cast(__half2, r.z)); b.x = f.x; b.y = f.y;
  f = __half22float2(__builtin_bit_cast(__half2, r.w)); b.z = f.x; b.w = f.y;
}

template <int H>
__global__ __launch_bounds__(256) void k_gat(const __half* __restrict__ xl,
                                             const __half* __restrict__ xr,
                                             const float* __restrict__ att,
                                             const float* __restrict__ bias,
                                             const int* __restrict__ deg,
                                             const int* __restrict__ ebuf,
                                             float* __restrict__ out) {
  constexpr int F = H * 32;
  constexpr int F8 = F / 8;        // 16B chunks (8 halfs) per row
  constexpr int F4 = F / 4;        // float4 per fp32 out row
  constexpr int LPE = F8;          // lanes per edge: 16 / 8 / 4
  constexpr int EPI = 64 / LPE;    // edges per iteration: 4 / 8 / 16
  constexpr float LOG2E = 1.44269504088896f;
  const int lane = threadIdx.x & 63;
  const int node = (blockIdx.x * blockDim.x + threadIdx.x) >> 6;
  if (node >= N) return;
  const int li = lane & (LPE - 1);  // 16B chunk index within row
  const int eg = lane / LPE;

  const uint4* xl4 = reinterpret_cast<const uint4*>(xl);
  const uint4* xr4 = reinterpret_cast<const uint4*>(xr);

  float4 xi0, xi1;
  cvt8(xr4[(unsigned)node * F8 + li], xi0, xi1);
  float4 at0 = reinterpret_cast<const float4*>(att)[li * 2];
  float4 at1 = reinterpret_cast<const float4*>(att)[li * 2 + 1];
  at0.x *= LOG2E; at0.y *= LOG2E; at0.z *= LOG2E; at0.w *= LOG2E;
  at1.x *= LOG2E; at1.y *= LOG2E; at1.z *= LOG2E; at1.w *= LOG2E;

  float4 acc0 = make_float4(0.f, 0.f, 0.f, 0.f);
  float4 acc1 = make_float4(0.f, 0.f, 0.f, 0.f);
  float l = 0.f;

  const int* row = ebuf + node * S;
  const int dn = min(deg[node], S);   // deg >= 1 (self loop)
  const int last = dn - 1;
  const int iters = (dn + EPI - 1) / EPI;

  auto process = [&](const uint4& raw, bool valid) {
    float4 j0, j1;
    cvt8(raw, j0, j1);
    float v0 = xi0.x + j0.x; v0 = fmaxf(v0, 0.2f * v0);
    float v1 = xi0.y + j0.y; v1 = fmaxf(v1, 0.2f * v1);
    float v2 = xi0.z + j0.z; v2 = fmaxf(v2, 0.2f * v2);
    float v3 = xi0.w + j0.w; v3 = fmaxf(v3, 0.2f * v3);
    float v4 = xi1.x + j1.x; v4 = fmaxf(v4, 0.2f * v4);
    float v5 = xi1.y + j1.y; v5 = fmaxf(v5, 0.2f * v5);
    float v6 = xi1.z + j1.z; v6 = fmaxf(v6, 0.2f * v6);
    float v7 = xi1.w + j1.w; v7 = fmaxf(v7, 0.2f * v7);
    float t = at0.x * v0;
    t = fmaf(at0.y, v1, t);
    t = fmaf(at0.z, v2, t);
    t = fmaf(at0.w, v3, t);
    t = fmaf(at1.x, v4, t);
    t = fmaf(at1.y, v5, t);
    t = fmaf(at1.z, v6, t);
    t = fmaf(at1.w, v7, t);
    // head = one 4-lane quad: butterfly via quad_perm DPP (VALU, no LDS pipe)
    t = dpp_add<0xB1>(t);   // xor 1: [1,0,3,2]
    t = dpp_add<0x4E>(t);   // xor 2: [2,3,0,1]
    float pm = valid ? exp2f(t) : 0.f;
    l += pm;
    acc0.x = fmaf(pm, j0.x, acc0.x); acc0.y = fmaf(pm, j0.y, acc0.y);
    acc0.z = fmaf(pm, j0.z, acc0.z); acc0.w = fmaf(pm, j0.w, acc0.w);
    acc1.x = fmaf(pm, j1.x, acc1.x); acc1.y = fmaf(pm, j1.y, acc1.y);
    acc1.z = fmaf(pm, j1.z, acc1.z); acc1.w = fmaf(pm, j1.w, acc1.w);
  };

  // pipeline warm-up: src prefetched 2 iterations ahead, gather 1 ahead
  int i = eg;
  bool vA = i < dn;
  int s0 = row[min(i, last)];
  i += EPI;
  uint4 xjA = xl4[(unsigned)s0 * F8 + li];
  bool vB = i < dn;
  int sN = row[min(i, last)];
  i += EPI;
  uint4 xjB;

  for (int it = 0; it < iters; it += 2) {
    // ---- phase A: consume (xjA, vA) = iteration it ----
    xjB = xl4[(unsigned)sN * F8 + li];             // gather it+1
    bool vn = i < dn;
    sN = row[min(i, last)];                        // src it+2
    i += EPI;
    process(xjA, vA);
    vA = vn;
    // ---- phase B: consume (xjB, vB) = iteration it+1 ----
    xjA = xl4[(unsigned)sN * F8 + li];             // gather it+2
    vn = i < dn;
    sN = row[min(i, last)];                        // src it+3
    i += EPI;
    process(xjB, vB);
    vB = vn;
  }

  // combine the EPI edge slots (once per node)
  #pragma unroll
  for (int ofs = LPE; ofs < 64; ofs <<= 1) {
    acc0.x += __shfl_xor(acc0.x, ofs);
    acc0.y += __shfl_xor(acc0.y, ofs);
    acc0.z += __shfl_xor(acc0.z, ofs);
    acc0.w += __shfl_xor(acc0.w, ofs);
    acc1.x += __shfl_xor(acc1.x, ofs);
    acc1.y += __shfl_xor(acc1.y, ofs);
    acc1.z += __shfl_xor(acc1.z, ofs);
    acc1.w += __shfl_xor(acc1.w, ofs);
    l      += __shfl_xor(l, ofs);
  }

  if (lane < LPE) {
    const float inv = 1.f / (l + 1e-16f);
    const float4 bv0 = reinterpret_cast<const float4*>(bias)[li * 2];
    const float4 bv1 = reinterpret_cast<const float4*>(bias)[li * 2 + 1];
    float4 r0, r1;
    r0.x = fmaxf(acc0.x * inv + bv0.x, 0.f);
    r0.y = fmaxf(acc0.y * inv + bv0.y, 0.f);
    r0.z = fmaxf(acc0.z * inv + bv0.z, 0.f);
    r0.w = fmaxf(acc0.w * inv + bv0.w, 0.f);
    r1.x = fmaxf(acc1.x * inv + bv1.x, 0.f);
    r1.y = fmaxf(acc1.y * inv + bv1.y, 0.f);
    r1.z = fmaxf(acc1.z * inv + bv1.z, 0.f);
    r1.w = fmaxf(acc1.w * inv + bv1.w, 0.f);
    float4* op = reinterpret_cast<float4*>(out) + (unsigned)node * F4 + li * 2;
    op[0] = r0;
    op[1] = r1;
  }
}

// ---------------- MLP head + output transforms ----------------

__global__ __launch_bounds__(256) void k_mlp(const float* __restrict__ h,
                                             const float* __restrict__ wm1,
                                             const float* __restrict__ bm1,
                                             const float* __restrict__ wm2,
                                             const float* __restrict__ bm2,
                                             float* __restrict__ out) {
  __shared__ float w1[512], b1[16], w2[32], b2[2];
  const int tid = threadIdx.x;
  for (int i = tid; i < 512; i += 256) w1[i] = wm1[i];
  if (tid < 16) b1[tid] = bm1[tid];
  if (tid < 32) w2[tid] = wm2[tid];
  if (tid < 2)  b2[tid] = bm2[tid];
  __syncthreads();
  const int node = blockIdx.x * blockDim.x + tid;
  if (node >= N) return;
  float hv[32];
  const float* hp = h + (size_t)node * 32;
  #pragma unroll
  for (int k = 0; k < 8; ++k) {
    float4 v = reinterpret_cast<const float4*>(hp)[k];
    hv[4 * k] = v.x; hv[4 * k + 1] = v.y; hv[4 * k + 2] = v.z; hv[4 * k + 3] = v.w;
  }
  float r0 = b2[0], r1 = b2[1];
  #pragma unroll
  for (int j = 0; j < 16; ++j) {
    float a = b1[j];
    #pragma unroll
    for (int k = 0; k < 32; ++k) a += hv[k] * w1[k * 16 + j];
    a = fmaxf(a, 0.f);
    r0 += a * w2[j * 2];
    r1 += a * w2[j * 2 + 1];
  }
  float vm = 1.f / (1.f + __expf(-r0)) + 0.5f;
  float va = tanhf(r1) * 180.f;
  out[(size_t)node * 2]     = vm;
  out[(size_t)node * 2 + 1] = va;
}

// ---------------- launch ----------------

extern "C" void kernel_launch(void* const* d_in, const int* in_sizes, int n_in,
                              void* d_out, int out_size, void* d_ws, size_t ws_size,
                              hipStream_t stream) {
  const float* x   = (const float*)d_in[0];
  const int*   ei  = (const int*)d_in[1];
  const float* w1l = (const float*)d_in[2];
  const float* b1l = (const float*)d_in[3];
  const float* w1r = (const float*)d_in[4];
  const float* b1r = (const float*)d_in[5];
  const float* a1  = (const float*)d_in[6];
  const float* c1  = (const float*)d_in[7];
  const float* w2l = (const float*)d_in[8];
  const float* b2l = (const float*)d_in[9];
  const float* w2r = (const float*)d_in[10];
  const float* b2r = (const float*)d_in[11];
  const float* a2  = (const float*)d_in[12];
  const float* c2  = (const float*)d_in[13];
  const float* w3l = (const float*)d_in[14];
  const float* b3l = (const float*)d_in[15];
  const float* w3r = (const float*)d_in[16];
  const float* b3r = (const float*)d_in[17];
  const float* a3  = (const float*)d_in[18];
  const float* c3  = (const float*)d_in[19];
  const float* wm1 = (const float*)d_in[20];
  const float* bm1 = (const float*)d_in[21];
  const float* wm2 = (const float*)d_in[22];
  const float* bm2 = (const float*)d_in[23];
  float* outp = (float*)d_out;
  (void)in_sizes; (void)n_in; (void)out_size; (void)ws_size;

  char* ws = (char*)d_ws;
  size_t o = 0;
  auto take = [&](size_t bytes) {
    char* p = ws + o;
    o = (o + bytes + 255) & ~(size_t)255;
    return p;
  };
  int* deg    = (int*)take((size_t)N * sizeof(int));
  int* ebuf   = (int*)take((size_t)N * S * sizeof(int));
  __half* A   = (__half*)take((size_t)N * 128 * sizeof(__half));  // xl (fp16)
  __half* B   = (__half*)take((size_t)N * 128 * sizeof(__half));  // xr (fp16)
  float* Cb   = (float*)take((size_t)N * 128 * sizeof(float));    // h (layer out)

  hipMemsetAsync(deg, 0, (size_t)N * sizeof(int), stream);

  // --- layer 1 fused with graph build: build blocks first, xform fills in ---
  k_l1<<<BUILD_B + 2 * XF_B, 256, 0, stream>>>(x, w1l, b1l, w1r, b1r, A, B,
                                               ei, deg, ebuf);
  k_gat<4><<<N / 4, 256, 0, stream>>>(A, B, a1, c1, deg, ebuf, Cb);

  // --- layer 2: 128 -> (2 heads x 32), concat ---
  k_xform2<128, 64, 2><<<2 * XF_B, 256, 0, stream>>>(Cb, w2l, b2l, w2r, b2r, A, B);
  k_gat<2><<<N / 4, 256, 0, stream>>>(A, B, a2, c2, deg, ebuf, Cb);

  // --- layer 3: 64 -> (1 head x 32), mean over 1 head == identity ---
  k_xform2<64, 32, 1><<<2 * XF_B, 256, 0, stream>>>(Cb, w3l, b3l, w3r, b3r, A, B);
  k_gat<1><<<N / 4, 256, 0, stream>>>(A, B, a3, c3, deg, ebuf, Cb);

  // --- MLP head + sigmoid/tanh ---
  k_mlp<<<(N + 255) / 256, 256, 0, stream>>>(Cb, wm1, bm1, wm2, bm2, outp);
}